// Round 3
// baseline (893.104 us; speedup 1.0000x reference)
//
#include <hip/hip_runtime.h>

typedef short  bfrag  __attribute__((ext_vector_type(8)));
typedef float  facc4  __attribute__((ext_vector_type(4)));
typedef unsigned short u16;
typedef unsigned int   u32;

#define MROWS 131072   // B*N = 256*512
#define DD    96

__device__ __forceinline__ u16 f2b(float f) {
  u32 u = __float_as_uint(f);
  return (u16)((u + 0x7FFFu + ((u >> 16) & 1u)) >> 16);   // RNE to bf16
}
__device__ __forceinline__ float b2f(u16 h) {
  return __uint_as_float(((u32)h) << 16);
}
__device__ __forceinline__ void splitf(float x, u16& h, u16& l) {
  h = f2b(x);
  l = f2b(x - b2f(h));
}
__device__ __forceinline__ void split4(float4 v, ushort4& oh, ushort4& ol) {
  splitf(v.x, oh.x, ol.x); splitf(v.y, oh.y, ol.y);
  splitf(v.z, oh.z, ol.z); splitf(v.w, oh.w, ol.w);
}

#define MFMA __builtin_amdgcn_mfma_f32_16x16x32_bf16

// ---------------- prep: split weights to hi/lo bf16, n-major; fold biases ------
__global__ void k_prep(const float* __restrict__ Wenc,
                       const float* __restrict__ benc,
                       const float* __restrict__ Wz0, const float* __restrict__ Wz1,
                       const float* __restrict__ Wr0, const float* __restrict__ Wr1,
                       const float* __restrict__ Wh0, const float* __restrict__ Wh1,
                       const float* __restrict__ bz0, const float* __restrict__ bz1,
                       const float* __restrict__ br0, const float* __restrict__ br1,
                       const float* __restrict__ bh0, const float* __restrict__ bh1,
                       u16* __restrict__ wencTh, u16* __restrict__ wencTl,
                       u16* __restrict__ wzrTh,  u16* __restrict__ wzrTl,
                       u16* __restrict__ whTh,   u16* __restrict__ whTl,
                       float* __restrict__ bias)
{
  int i = blockIdx.x * 256 + threadIdx.x;
  if (i < 36864) {                       // wencT [96][384] (K padded 300->384)
    int n = i / 384, k = i % 384;
    float v = (k < 300) ? Wenc[k * 96 + n] : 0.f;
    u16 h, l; splitf(v, h, l);
    wencTh[i] = h; wencTl[i] = l;
  } else if (i < 73728) {                // wzrT [2][96][192]: g=0 [Wz0;Wz1], g=1 [Wr0;Wr1]
    int j = i - 36864;
    int g = j / 18432, r = j % 18432;
    int n = r / 192, k = r % 192;
    const float* W0 = g ? Wr0 : Wz0;
    const float* W1 = g ? Wr1 : Wz1;
    float v = (k < 96) ? W0[k * 96 + n] : W1[(k - 96) * 96 + n];
    u16 h, l; splitf(v, h, l);
    wzrTh[j] = h; wzrTl[j] = l;
  } else if (i < 92160) {                // whT [96][192]: [Wh0;Wh1]
    int j = i - 73728;
    int n = j / 192, k = j % 192;
    float v = (k < 96) ? Wh0[k * 96 + n] : Wh1[(k - 96) * 96 + n];
    u16 h, l; splitf(v, h, l);
    whTh[j] = h; whTl[j] = l;
  } else if (i < 92544) {                // bias [4][96]: enc, z, r, h
    int j = i - 92160;
    int r = j / 96, n = j % 96;
    float v;
    if      (r == 0) v = benc[n];
    else if (r == 1) v = bz0[n] + bz1[n];
    else if (r == 2) v = br0[n] + br1[n];
    else             v = bh0[n] + bh1[n];
    bias[j] = v;
  }
}

// ---------------- encoder: xf = (mask*relu(x)) @ Wenc + benc  (fp32 out) -------
__global__ __launch_bounds__(256) void k_enc(const float* __restrict__ x,
    const float* __restrict__ mask,
    const u16* __restrict__ wTh, const u16* __restrict__ wTl,
    const float* __restrict__ bias, float* __restrict__ xf)
{
  __shared__ u16 sAh[128][72], sAl[128][72];
  __shared__ u16 sBh[96][72],  sBl[96][72];
  const int tid = threadIdx.x;
  const int wave = tid >> 6, lane = tid & 63, q = lane >> 4, l15 = lane & 15;
  const int m0 = blockIdx.x * 128;
  facc4 acc[2][6] = {};
  for (int c = 0; c < 5; ++c) {          // K = 300, chunks of 64 (last partial)
    int k0 = c * 64;
    { // A stage: fp32 -> relu*mask -> split
      int rl = tid >> 2, cg = tid & 3;
      for (int it = 0; it < 2; ++it) {
        int row = rl + it * 64;
        int grow = m0 + row;
        float mk = mask[grow];
        const float* xr = x + (size_t)grow * 300 + k0;
        #pragma unroll
        for (int j = 0; j < 4; ++j) {
          int kk = (cg + j * 4) * 4;
          float4 v;
          if (k0 + kk + 4 <= 300) v = *(const float4*)(xr + kk);
          else                    v = make_float4(0.f, 0.f, 0.f, 0.f);
          v.x = fmaxf(v.x, 0.f) * mk; v.y = fmaxf(v.y, 0.f) * mk;
          v.z = fmaxf(v.z, 0.f) * mk; v.w = fmaxf(v.w, 0.f) * mk;
          ushort4 oh, ol; split4(v, oh, ol);
          *(ushort4*)&sAh[row][kk] = oh;
          *(ushort4*)&sAl[row][kk] = ol;
        }
      }
    }
    { // B stage: straight copies (pre-split weights)
      for (int u = tid; u < 768; u += 256) {
        int n = u >> 3, kk = (u & 7) * 8;
        size_t off = (size_t)n * 384 + k0 + kk;
        *(uint4*)&sBh[n][kk] = *(const uint4*)(wTh + off);
        *(uint4*)&sBl[n][kk] = *(const uint4*)(wTl + off);
      }
    }
    __syncthreads();
    #pragma unroll
    for (int ks = 0; ks < 2; ++ks) {
      int kb = ks * 32 + q * 8;
      bfrag a0h = *(const bfrag*)&sAh[wave * 32 + l15][kb];
      bfrag a0l = *(const bfrag*)&sAl[wave * 32 + l15][kb];
      bfrag a1h = *(const bfrag*)&sAh[wave * 32 + 16 + l15][kb];
      bfrag a1l = *(const bfrag*)&sAl[wave * 32 + 16 + l15][kb];
      #pragma unroll
      for (int nt = 0; nt < 6; ++nt) {
        bfrag bh = *(const bfrag*)&sBh[nt * 16 + l15][kb];
        bfrag bl = *(const bfrag*)&sBl[nt * 16 + l15][kb];
        acc[0][nt] = MFMA(a0h, bh, acc[0][nt], 0, 0, 0);
        acc[0][nt] = MFMA(a0h, bl, acc[0][nt], 0, 0, 0);
        acc[0][nt] = MFMA(a0l, bh, acc[0][nt], 0, 0, 0);
        acc[1][nt] = MFMA(a1h, bh, acc[1][nt], 0, 0, 0);
        acc[1][nt] = MFMA(a1h, bl, acc[1][nt], 0, 0, 0);
        acc[1][nt] = MFMA(a1l, bh, acc[1][nt], 0, 0, 0);
      }
    }
    __syncthreads();
  }
  #pragma unroll
  for (int mt = 0; mt < 2; ++mt)
  #pragma unroll
  for (int rg = 0; rg < 4; ++rg) {
    int row = m0 + wave * 32 + mt * 16 + q * 4 + rg;
    #pragma unroll
    for (int nt = 0; nt < 6; ++nt) {
      int col = nt * 16 + l15;
      xf[(size_t)row * 96 + col] = acc[mt][nt][rg] + bias[col];
    }
  }
}

// ---------------- agg: af = adj @ xf  (batched, fp32 out; B transposed on the fly)
__global__ __launch_bounds__(256) void k_agg(const float* __restrict__ adj,
    const float* __restrict__ xf, float* af)
{
  __shared__ u16 sAh[128][72], sAl[128][72];
  __shared__ u16 sBh[96][72],  sBl[96][72];
  const int tid = threadIdx.x;
  const int wave = tid >> 6, lane = tid & 63, q = lane >> 4, l15 = lane & 15;
  const int bb = blockIdx.y;
  const int m0 = blockIdx.x * 128;
  const float* A = adj + (size_t)bb * 512 * 512;
  const float* X = xf  + (size_t)bb * 512 * 96;
  facc4 acc[2][6] = {};
  for (int c = 0; c < 8; ++c) {
    int k0 = c * 64;
    { // A stage: adj fp32 -> split
      int rl = tid >> 2, cg = tid & 3;
      for (int it = 0; it < 2; ++it) {
        int row = rl + it * 64;
        const float* ar_ = A + (size_t)(m0 + row) * 512 + k0;
        #pragma unroll
        for (int j = 0; j < 4; ++j) {
          int kk = (cg + j * 4) * 4;
          float4 v = *(const float4*)(ar_ + kk);
          ushort4 oh, ol; split4(v, oh, ol);
          *(ushort4*)&sAh[row][kk] = oh;
          *(ushort4*)&sAl[row][kk] = ol;
        }
      }
    }
    { // B stage: transpose 64 nodes x 96 d from row-major xf, split
      int node = tid >> 2, seg = tid & 3;
      const float* xp = X + (size_t)(k0 + node) * 96;
      #pragma unroll
      for (int j = 0; j < 6; ++j) {
        int d = seg * 24 + j * 4;
        float4 v = *(const float4*)(xp + d);
        u16 h, l;
        splitf(v.x, h, l); sBh[d    ][node] = h; sBl[d    ][node] = l;
        splitf(v.y, h, l); sBh[d + 1][node] = h; sBl[d + 1][node] = l;
        splitf(v.z, h, l); sBh[d + 2][node] = h; sBl[d + 2][node] = l;
        splitf(v.w, h, l); sBh[d + 3][node] = h; sBl[d + 3][node] = l;
      }
    }
    __syncthreads();
    #pragma unroll
    for (int ks = 0; ks < 2; ++ks) {
      int kb = ks * 32 + q * 8;
      bfrag a0h = *(const bfrag*)&sAh[wave * 32 + l15][kb];
      bfrag a0l = *(const bfrag*)&sAl[wave * 32 + l15][kb];
      bfrag a1h = *(const bfrag*)&sAh[wave * 32 + 16 + l15][kb];
      bfrag a1l = *(const bfrag*)&sAl[wave * 32 + 16 + l15][kb];
      #pragma unroll
      for (int nt = 0; nt < 6; ++nt) {
        bfrag bh = *(const bfrag*)&sBh[nt * 16 + l15][kb];
        bfrag bl = *(const bfrag*)&sBl[nt * 16 + l15][kb];
        acc[0][nt] = MFMA(a0h, bh, acc[0][nt], 0, 0, 0);
        acc[0][nt] = MFMA(a0h, bl, acc[0][nt], 0, 0, 0);
        acc[0][nt] = MFMA(a0l, bh, acc[0][nt], 0, 0, 0);
        acc[1][nt] = MFMA(a1h, bh, acc[1][nt], 0, 0, 0);
        acc[1][nt] = MFMA(a1h, bl, acc[1][nt], 0, 0, 0);
        acc[1][nt] = MFMA(a1l, bh, acc[1][nt], 0, 0, 0);
      }
    }
    __syncthreads();
  }
  #pragma unroll
  for (int mt = 0; mt < 2; ++mt)
  #pragma unroll
  for (int rg = 0; rg < 4; ++rg) {
    int row = m0 + wave * 32 + mt * 16 + q * 4 + rg;
    size_t grow = (size_t)bb * 512 + row;
    #pragma unroll
    for (int nt = 0; nt < 6; ++nt) {
      int col = nt * 16 + l15;
      af[grow * 96 + col] = acc[mt][nt][rg];
    }
  }
}

// ---------------- fused GRU: z,r,h + gate in one kernel (z stays fp32 in regs) --
// af aliases d_out; outp aliases d_out; xf is read+written. No __restrict__ on those.
__global__ __launch_bounds__(256) void k_gru(const float* af, float* xf,
    const u16* __restrict__ wzrTh, const u16* __restrict__ wzrTl,
    const u16* __restrict__ whTh,  const u16* __restrict__ whTl,
    const float* __restrict__ bias, const float* __restrict__ mask,
    float* outp, const int last)
{
  __shared__ u16 sAh[128][40],  sAl[128][40];
  __shared__ u16 sBzh[96][40],  sBzl[96][40];   // Wz chunks (GEMM1), Wh chunks (GEMM2)
  __shared__ u16 sBrh[96][40],  sBrl[96][40];   // Wr chunks (GEMM1)
  __shared__ u16 sRxh[128][104], sRxl[128][104]; // r*x tile, split
  const int tid = threadIdx.x;
  const int wave = tid >> 6, lane = tid & 63, q = lane >> 4, l15 = lane & 15;
  const int m0 = blockIdx.x * 128;

  // ---- GEMM1: az = [a|x]@[Wz0;Wz1], ar = [a|x]@[Wr0;Wr1] ----
  facc4 az[2][6] = {}, ar[2][6] = {};
  for (int c = 0; c < 6; ++c) {          // K = 192, chunks of 32
    const float* Asrc = (c < 3) ? af : xf;
    int ka = (c < 3 ? c : c - 3) * 32;
    {
      int row = tid >> 1, hf = tid & 1;
      const float* ap = Asrc + (size_t)(m0 + row) * 96 + ka + hf * 16;
      #pragma unroll
      for (int j = 0; j < 4; ++j) {
        int kk = hf * 16 + j * 4;
        float4 v = *(const float4*)(ap + j * 4);
        ushort4 oh, ol; split4(v, oh, ol);
        *(ushort4*)&sAh[row][kk] = oh;
        *(ushort4*)&sAl[row][kk] = ol;
      }
    }
    {
      int kw = c * 32;
      for (int u = tid; u < 384; u += 256) {
        int n = u >> 2, kk = (u & 3) * 8;
        size_t off = (size_t)n * 192 + kw + kk;
        *(uint4*)&sBzh[n][kk] = *(const uint4*)(wzrTh + off);
        *(uint4*)&sBzl[n][kk] = *(const uint4*)(wzrTl + off);
        *(uint4*)&sBrh[n][kk] = *(const uint4*)(wzrTh + 18432 + off);
        *(uint4*)&sBrl[n][kk] = *(const uint4*)(wzrTl + 18432 + off);
      }
    }
    __syncthreads();
    int kb = q * 8;
    bfrag a0h = *(const bfrag*)&sAh[wave * 32 + l15][kb];
    bfrag a0l = *(const bfrag*)&sAl[wave * 32 + l15][kb];
    bfrag a1h = *(const bfrag*)&sAh[wave * 32 + 16 + l15][kb];
    bfrag a1l = *(const bfrag*)&sAl[wave * 32 + 16 + l15][kb];
    #pragma unroll
    for (int nt = 0; nt < 6; ++nt) {
      bfrag bh = *(const bfrag*)&sBzh[nt * 16 + l15][kb];
      bfrag bl = *(const bfrag*)&sBzl[nt * 16 + l15][kb];
      az[0][nt] = MFMA(a0h, bh, az[0][nt], 0, 0, 0);
      az[0][nt] = MFMA(a0h, bl, az[0][nt], 0, 0, 0);
      az[0][nt] = MFMA(a0l, bh, az[0][nt], 0, 0, 0);
      az[1][nt] = MFMA(a1h, bh, az[1][nt], 0, 0, 0);
      az[1][nt] = MFMA(a1h, bl, az[1][nt], 0, 0, 0);
      az[1][nt] = MFMA(a1l, bh, az[1][nt], 0, 0, 0);
      bfrag ch = *(const bfrag*)&sBrh[nt * 16 + l15][kb];
      bfrag cl = *(const bfrag*)&sBrl[nt * 16 + l15][kb];
      ar[0][nt] = MFMA(a0h, ch, ar[0][nt], 0, 0, 0);
      ar[0][nt] = MFMA(a0h, cl, ar[0][nt], 0, 0, 0);
      ar[0][nt] = MFMA(a0l, ch, ar[0][nt], 0, 0, 0);
      ar[1][nt] = MFMA(a1h, ch, ar[1][nt], 0, 0, 0);
      ar[1][nt] = MFMA(a1h, cl, ar[1][nt], 0, 0, 0);
      ar[1][nt] = MFMA(a1l, ch, ar[1][nt], 0, 0, 0);
    }
    __syncthreads();
  }

  // ---- gates: z (keep fp32 in az), rx = sigmoid(ar+br)*x -> LDS split ----
  #pragma unroll
  for (int mt = 0; mt < 2; ++mt)
  #pragma unroll
  for (int rg = 0; rg < 4; ++rg) {
    int row = m0 + wave * 32 + mt * 16 + q * 4 + rg;
    #pragma unroll
    for (int nt = 0; nt < 6; ++nt) {
      int col = nt * 16 + l15;
      float vz = az[mt][nt][rg] + bias[96 + col];
      float vr = ar[mt][nt][rg] + bias[192 + col];
      float z = 1.f / (1.f + __expf(-vz));
      float r = 1.f / (1.f + __expf(-vr));
      az[mt][nt][rg] = z;                       // keep z in registers
      float rx = r * xf[(size_t)row * 96 + col];
      u16 h, l; splitf(rx, h, l);
      sRxh[row - m0][col] = h;
      sRxl[row - m0][col] = l;
    }
  }
  __syncthreads();

  // ---- GEMM2: ah = [a|rx]@[Wh0;Wh1] ----
  facc4 ah[2][6] = {};
  for (int c = 0; c < 6; ++c) {
    if (c < 3) {                                // A = a chunk from global, split
      int row = tid >> 1, hf = tid & 1;
      const float* ap = af + (size_t)(m0 + row) * 96 + c * 32 + hf * 16;
      #pragma unroll
      for (int j = 0; j < 4; ++j) {
        int kk = hf * 16 + j * 4;
        float4 v = *(const float4*)(ap + j * 4);
        ushort4 oh, ol; split4(v, oh, ol);
        *(ushort4*)&sAh[row][kk] = oh;
        *(ushort4*)&sAl[row][kk] = ol;
      }
    }
    {
      int kw = c * 32;
      for (int u = tid; u < 384; u += 256) {
        int n = u >> 2, kk = (u & 3) * 8;
        size_t off = (size_t)n * 192 + kw + kk;
        *(uint4*)&sBzh[n][kk] = *(const uint4*)(whTh + off);
        *(uint4*)&sBzl[n][kk] = *(const uint4*)(whTl + off);
      }
    }
    __syncthreads();
    int kb = q * 8;
    bfrag a0h, a0l, a1h, a1l;
    if (c < 3) {
      a0h = *(const bfrag*)&sAh[wave * 32 + l15][kb];
      a0l = *(const bfrag*)&sAl[wave * 32 + l15][kb];
      a1h = *(const bfrag*)&sAh[wave * 32 + 16 + l15][kb];
      a1l = *(const bfrag*)&sAl[wave * 32 + 16 + l15][kb];
    } else {
      int ko = (c - 3) * 32 + kb;
      a0h = *(const bfrag*)&sRxh[wave * 32 + l15][ko];
      a0l = *(const bfrag*)&sRxl[wave * 32 + l15][ko];
      a1h = *(const bfrag*)&sRxh[wave * 32 + 16 + l15][ko];
      a1l = *(const bfrag*)&sRxl[wave * 32 + 16 + l15][ko];
    }
    #pragma unroll
    for (int nt = 0; nt < 6; ++nt) {
      bfrag bh = *(const bfrag*)&sBzh[nt * 16 + l15][kb];
      bfrag bl = *(const bfrag*)&sBzl[nt * 16 + l15][kb];
      ah[0][nt] = MFMA(a0h, bh, ah[0][nt], 0, 0, 0);
      ah[0][nt] = MFMA(a0h, bl, ah[0][nt], 0, 0, 0);
      ah[0][nt] = MFMA(a0l, bh, ah[0][nt], 0, 0, 0);
      ah[1][nt] = MFMA(a1h, bh, ah[1][nt], 0, 0, 0);
      ah[1][nt] = MFMA(a1h, bl, ah[1][nt], 0, 0, 0);
      ah[1][nt] = MFMA(a1l, bh, ah[1][nt], 0, 0, 0);
    }
    __syncthreads();
  }

  // ---- gate epilogue: out = x + z*(relu(mask*(h_pre+bh)) - x) ----
  #pragma unroll
  for (int mt = 0; mt < 2; ++mt)
  #pragma unroll
  for (int rg = 0; rg < 4; ++rg) {
    int row = m0 + wave * 32 + mt * 16 + q * 4 + rg;
    float mk = mask[row];
    #pragma unroll
    for (int nt = 0; nt < 6; ++nt) {
      int col = nt * 16 + l15;
      size_t idx = (size_t)row * 96 + col;
      float pre = ah[mt][nt][rg] + bias[288 + col];
      float hv  = fmaxf(mk * pre, 0.f);
      float zv  = az[mt][nt][rg];
      float xv  = xf[idx];
      float o   = xv + zv * (hv - xv);
      if (last) outp[idx] = o;
      else      xf[idx]   = o;
    }
  }
}

extern "C" void kernel_launch(void* const* d_in, const int* in_sizes, int n_in,
                              void* d_out, int out_size, void* d_ws, size_t ws_size,
                              hipStream_t stream)
{
  const float* x    = (const float*)d_in[0];
  const float* adj  = (const float*)d_in[1];
  const float* mask = (const float*)d_in[2];
  const float* Wenc = (const float*)d_in[3];
  const float* benc = (const float*)d_in[4];
  const float* Wz0  = (const float*)d_in[5];
  const float* Wz1  = (const float*)d_in[6];
  const float* Wr0  = (const float*)d_in[7];
  const float* Wr1  = (const float*)d_in[8];
  const float* Wh0  = (const float*)d_in[9];
  const float* Wh1  = (const float*)d_in[10];
  const float* bz0  = (const float*)d_in[11];
  const float* bz1  = (const float*)d_in[12];
  const float* br0  = (const float*)d_in[13];
  const float* br1  = (const float*)d_in[14];
  const float* bh0  = (const float*)d_in[15];
  const float* bh1  = (const float*)d_in[16];

  char* ws = (char*)d_ws;
  const size_t NEL = (size_t)MROWS * DD;            // 12,582,912
  float* xf   = (float*)(ws);                       // 50,331,648 B
  char*  wb   = ws + 4 * NEL;
  u16* wencTh = (u16*)(wb);                         // 73,728 B
  u16* wencTl = (u16*)(wb + 73728);
  u16* wzrTh  = (u16*)(wb + 147456);                // 73,728 B
  u16* wzrTl  = (u16*)(wb + 221184);
  u16* whTh   = (u16*)(wb + 294912);                // 36,864 B
  u16* whTl   = (u16*)(wb + 331776);
  float* bias = (float*)(wb + 368640);              // 1,536 B

  float* af   = (float*)d_out;                      // a-buffer aliases d_out
  float* outp = (float*)d_out;

  k_prep<<<362, 256, 0, stream>>>(Wenc, benc, Wz0, Wz1, Wr0, Wr1, Wh0, Wh1,
                                  bz0, bz1, br0, br1, bh0, bh1,
                                  wencTh, wencTl, wzrTh, wzrTl, whTh, whTl, bias);
  k_enc<<<dim3(MROWS / 128), 256, 0, stream>>>(x, mask, wencTh, wencTl, bias, xf);
  for (int s = 0; s < 2; ++s) {
    int last = (s == 1);
    k_agg<<<dim3(4, 256), 256, 0, stream>>>(adj, xf, af);
    k_gru<<<dim3(MROWS / 128), 256, 0, stream>>>(af, xf, wzrTh, wzrTl, whTh, whTl,
                                                 bias, mask, outp, last);
  }
}